// Round 9
// baseline (41.759 us; speedup 1.0000x reference)
//
#include <hip/hip_runtime.h>
#include <hip/hip_bf16.h>

// Problem constants (B=4, T=4096, C=2048, E=64)
#define N_TOK   16384
#define C_DIM   2048
#define E_DIM   64
#define P_OFF   (N_TOK * E_DIM)        // 1048576 — end of probs section
#define FB_OFF  P_OFF                  // fallback_count scalar
#define LG_OFF  (P_OFF + 1)            // logits section
#define AM_OFF  (2 * P_OFF + 1)        // activation_mask section

#define BPK_BYTES  262144              // 256 KB prepacked B
#define PART_BYTES ((size_t)4 * N_TOK * E_DIM * 2)   // 8.4 MB bf16 partials

typedef __attribute__((ext_vector_type(8))) short bf16x8;  // 8 bf16 in 4 VGPRs
typedef __attribute__((ext_vector_type(4))) float f32x4;

static __device__ __forceinline__ unsigned short f2bf_rtn(float f) {
    unsigned u = __float_as_uint(f);
    unsigned r = u + 0x7FFFu + ((u >> 16) & 1u);   // round-to-nearest-even
    return (unsigned short)(r >> 16);
}
static __device__ __forceinline__ float bf2f(unsigned short h) {
    return __uint_as_float(((unsigned)h) << 16);
}
static __device__ __forceinline__ short f2bf_hw(float f) {
    __hip_bfloat16 h = __float2bfloat16(f);     // HW cvt, pairs fuse to v_cvt_pk_bf16_f32
    return *reinterpret_cast<short*>(&h);
}

// ---------------------------------------------------------------------------
// Kernel 1: prepack sim_matrix [2048,64] f32 -> bf16 (RTN) MFMA fragments.
// kk-step it (32 k): layout [it(64)][nb(4)][lane(64)][i(8)] shorts (256 KB).
// Content: lane l, elem i -> sim[it*32 + (l>>4)*8 + i][nb*16 + (l&15)]
// Also zero-initializes the fallback counter in d_out.
// ---------------------------------------------------------------------------
__global__ void gating_prepack(const float* __restrict__ sim,
                               unsigned short* __restrict__ Bpk,
                               float* __restrict__ out) {
    int tid = blockIdx.x * 256 + threadIdx.x;
    if (tid == 0) out[FB_OFF] = 0.0f;
    if (tid >= C_DIM * E_DIM) return;
    int k = tid >> 6;
    int e = tid & 63;
    float v = sim[tid];                       // sim[k*64 + e]
    int it = k >> 5;                          // kk-step 0..63
    int gr = (k >> 3) & 3;
    int i  = k & 7;
    int lane = gr * 16 + (e & 15);
    int nb   = e >> 4;
    Bpk[it * 2048 + nb * 512 + lane * 8 + i] = f2bf_rtn(v);
}

// ---------------------------------------------------------------------------
// Phase 1: split-K GEMM. Grid 512 x 512 thr (8 waves; 64 KB LDS -> 2 blk/CU,
// 16 waves/CU). Block (kq = bid&3, tg = bid>>2): tokens tg*128..+127,
// K-range kq*512..+511 (16 kk-steps). B staged ONCE into LDS -> lgkmcnt only;
// A is the SOLE per-loop vmcnt stream.
//
// KEY (R9): sched_barrier(0) fences pin the A pipeline in program order.
// R3's profile showed VGPR_Count=44 for a source with a 64-VGPR ring: hipcc
// had sunk every "prefetch" to just-before-use, collapsing the pipeline.
// With fences {extract c | refill c+4 | compute c}, the refill loads cannot
// sink below the fence, so 3 chunks (~1000cy) genuinely stay in flight.
// Writes bf16 partials: part[kq][t][e0(16)][nb(4)] (ushort4 per lane).
// ---------------------------------------------------------------------------
__global__ __launch_bounds__(512, 4)
void gating_gemm(const float* __restrict__ x,
                 const unsigned short* __restrict__ Bpk,
                 unsigned short* __restrict__ part) {
    __shared__ unsigned short Blds[32768];   // 64 KB: B quarter

    const int tid = threadIdx.x;
    const int kq  = blockIdx.x & 3;
    const int tg  = blockIdx.x >> 2;

    // ---- stage B quarter: 512 thr x 8 x 16 B, linear ----
    const unsigned short* bq = Bpk + kq * 32768;
#pragma unroll
    for (int j = 0; j < 8; ++j) {
        __builtin_amdgcn_global_load_lds(
            (const __attribute__((address_space(1))) unsigned int*)(bq + j * 4096 + tid * 8),
            (__attribute__((address_space(3))) unsigned int*)(&Blds[j * 4096 + tid * 8]),
            16, 0, 0);
    }
    __syncthreads();

    const int l   = tid & 63;
    const int w   = tid >> 6;          // wave id 0..7 -> 16-token group
    const int g   = l >> 4;
    const int e0  = l & 15;
    const int trow0 = tg * 128 + w * 16;
    const float* xr = x + (size_t)(trow0 + e0) * C_DIM + kq * 512 + g * 8;

    f32x4 acc[4];
#pragma unroll
    for (int nb = 0; nb < 4; ++nb) acc[nb] = (f32x4)0.0f;

    // ---- A ring: 4 chunks x 2 kk-steps x 2 float4 = 64 VGPR ----
    float4 Ac[4][2][2];
#pragma unroll
    for (int c = 0; c < 4; ++c)
#pragma unroll
        for (int st = 0; st < 2; ++st) {
            const float* ap = xr + (c * 2 + st) * 32;
            Ac[c][st][0] = *(const float4*)ap;
            Ac[c][st][1] = *(const float4*)(ap + 4);
        }
    __builtin_amdgcn_sched_barrier(0);   // pin: all 4 prologue chunks issued here

    // ---- 8 chunks of 2 kk-steps, fully unrolled ----
#pragma unroll
    for (int c = 0; c < 8; ++c) {
        const int sl = c & 3;

        // (1) extract chunk c (vmcnt wait lands here, leaves c+1..c+3 in flight)
        float av[2][8];
#pragma unroll
        for (int st = 0; st < 2; ++st) {
            av[st][0] = Ac[sl][st][0].x; av[st][1] = Ac[sl][st][0].y;
            av[st][2] = Ac[sl][st][0].z; av[st][3] = Ac[sl][st][0].w;
            av[st][4] = Ac[sl][st][1].x; av[st][5] = Ac[sl][st][1].y;
            av[st][6] = Ac[sl][st][1].z; av[st][7] = Ac[sl][st][1].w;
        }
        __builtin_amdgcn_sched_barrier(0);

        // (2) issue refill: chunk c+4 into the just-freed slot
        if (c < 4) {
#pragma unroll
            for (int st = 0; st < 2; ++st) {
                const float* ap = xr + ((c + 4) * 2 + st) * 32;
                Ac[sl][st][0] = *(const float4*)ap;
                Ac[sl][st][1] = *(const float4*)(ap + 4);
            }
        }
        __builtin_amdgcn_sched_barrier(0);   // loads may not sink below this

        // (3) compute chunk c: pack (HW cvt) + 4 MFMA per step (B via ds_read_b128)
#pragma unroll
        for (int st = 0; st < 2; ++st) {
            const int it = c * 2 + st;
            bf16x8 ah;
#pragma unroll
            for (int i = 0; i < 8; ++i) ah[i] = f2bf_hw(av[st][i]);
#pragma unroll
            for (int nb = 0; nb < 4; ++nb) {
                bf16x8 bf = *(const bf16x8*)(&Blds[it * 2048 + nb * 512 + l * 8]);
                acc[nb] = __builtin_amdgcn_mfma_f32_16x16x32_bf16(ah, bf, acc[nb], 0, 0, 0);
            }
        }
        __builtin_amdgcn_sched_barrier(0);
    }

    // ---- store bf16 partials: ushort4 per (token, e0) ----
    ushort4* pp = (ushort4*)part;
#pragma unroll
    for (int r = 0; r < 4; ++r) {
        int t = trow0 + g * 4 + r;               // C/D row = (l>>4)*4 + reg
        ushort4 v;
        v.x = f2bf_rtn(acc[0][r]); v.y = f2bf_rtn(acc[1][r]);
        v.z = f2bf_rtn(acc[2][r]); v.w = f2bf_rtn(acc[3][r]);
        pp[(size_t)(kq * N_TOK + t) * 16 + e0] = v;
    }
}

// ---------------------------------------------------------------------------
// Phase 2: reduce 4 bf16 K-partials + gating epilogue.
// Grid 256 x 256 (4 waves). Block: 64 tokens; wave w: 16 tokens.
// Lane (g,e0) handles tokens t = blk*64 + w*16 + g*4 + r, experts nb*16+e0.
// ---------------------------------------------------------------------------
__global__ __launch_bounds__(256, 4)
void gating_epi(const unsigned short* __restrict__ part,
                const float* __restrict__ gates,
                float* __restrict__ out) {
    const int tid = threadIdx.x;
    const int l   = tid & 63;
    const int w   = tid >> 6;
    const int g   = l >> 4;
    const int e0  = l & 15;
    const ushort4* pp = (const ushort4*)part;

    float sig[4];
#pragma unroll
    for (int nb = 0; nb < 4; ++nb)
        sig[nb] = 1.0f / (1.0f + expf(-gates[nb * 16 + e0]));

#pragma unroll
    for (int r = 0; r < 4; ++r) {
        const int t = blockIdx.x * 64 + w * 16 + g * 4 + r;
        float tot[4] = {0.0f, 0.0f, 0.0f, 0.0f};
#pragma unroll
        for (int s = 0; s < 4; ++s) {
            ushort4 v = pp[(size_t)(s * N_TOK + t) * 16 + e0];
            tot[0] += bf2f(v.x); tot[1] += bf2f(v.y);
            tot[2] += bf2f(v.z); tot[3] += bf2f(v.w);
        }
        float lg[4] = {tot[0] - sig[0], tot[1] - sig[1],
                       tot[2] - sig[2], tot[3] - sig[3]};
        bool  act[4];
        int   lcnt = 0;
        float lmax = -3.4e38f;
#pragma unroll
        for (int nb = 0; nb < 4; ++nb) {
            act[nb] = lg[nb] > 0.0f;
            if (act[nb]) { lcnt++; lmax = fmaxf(lmax, lg[nb]); }
        }
        int cnt = lcnt;
        float mx = lmax;
#pragma unroll
        for (int m = 1; m < 16; m <<= 1) {
            cnt += __shfl_xor(cnt, m, 16);
            mx   = fmaxf(mx, __shfl_xor(mx, m, 16));
        }

        float p[4], am[4];
        if (cnt > 0) {
            float ex[4], ls = 0.0f;
#pragma unroll
            for (int nb = 0; nb < 4; ++nb) {
                ex[nb] = act[nb] ? expf(lg[nb] - mx) : 0.0f;
                ls += ex[nb];
            }
            float Z = ls;
#pragma unroll
            for (int m = 1; m < 16; m <<= 1) Z += __shfl_xor(Z, m, 16);
            float rz = 1.0f / Z;
#pragma unroll
            for (int nb = 0; nb < 4; ++nb) {
                p[nb]  = ex[nb] * rz;
                am[nb] = act[nb] ? 1.0f : 0.0f;
            }
        } else {
            // fallback: top-32 of 64 logits (ties -> lower expert index);
            // all logits <= 0 here, so probs are uniform 1/32 over the set.
            unsigned selm = 0;
            for (int it = 0; it < 32; ++it) {
                float bv = -3.4e38f;
                int   bi = 127;
#pragma unroll
                for (int nb = 0; nb < 4; ++nb) {
                    if (!((selm >> nb) & 1)) {
                        float v = lg[nb];
                        int   e = nb * 16 + e0;
                        if (v > bv || (v == bv && e < bi)) { bv = v; bi = e; }
                    }
                }
#pragma unroll
                for (int m = 1; m < 16; m <<= 1) {
                    float ov = __shfl_xor(bv, m, 16);
                    int   oi = __shfl_xor(bi, m, 16);
                    if (ov > bv || (ov == bv && oi < bi)) { bv = ov; bi = oi; }
                }
                if ((bi & 15) == e0) selm |= 1u << (bi >> 4);
            }
#pragma unroll
            for (int nb = 0; nb < 4; ++nb) {
                bool s_ = (selm >> nb) & 1;
                p[nb]  = s_ ? (1.0f / 32.0f) : 0.0f;
                am[nb] = s_ ? 1.0f : 0.0f;
            }
            if (e0 == 0) atomicAdd(&out[FB_OFF], 1.0f);
        }

#pragma unroll
        for (int nb = 0; nb < 4; ++nb) {
            int idx = t * 64 + nb * 16 + e0;
            out[idx]          = p[nb];
            out[LG_OFF + idx] = lg[nb];
            out[AM_OFF + idx] = am[nb];
        }
    }
}

// ---------------------------------------------------------------------------
// Fallback mono kernel (R5 structure) if ws_size can't hold the partials.
// ---------------------------------------------------------------------------
__global__ __launch_bounds__(256, 4)
void gating_mono(const float* __restrict__ x,
                 const unsigned short* __restrict__ Bpk,
                 const float* __restrict__ gates,
                 float* __restrict__ out) {
    __shared__ float red[4][16][64];

    const int tid = threadIdx.x;
    const int l   = tid & 63;
    const int w   = tid >> 6;
    const int row0 = blockIdx.x * 16;
    const int g    = l >> 4;
    const int e0   = l & 15;
    const float* xr = x + (size_t)(row0 + e0) * C_DIM + w * 512 + g * 8;
    const unsigned short* bw = Bpk + (size_t)w * 16 * 2048 + l * 8;

    f32x4 acc[4];
#pragma unroll
    for (int nb = 0; nb < 4; ++nb) acc[nb] = (f32x4)0.0f;

    bf16x8 Bf[2][4];
#pragma unroll
    for (int b = 0; b < 2; ++b)
#pragma unroll
        for (int f = 0; f < 4; ++f)
            Bf[b][f] = *(const bf16x8*)(bw + b * 2048 + f * 512);
    float4 Ar[4][2];
#pragma unroll
    for (int it = 0; it < 4; ++it) {
        const float* ap = xr + it * 32;
        Ar[it][0] = *(const float4*)ap;
        Ar[it][1] = *(const float4*)(ap + 4);
    }

#pragma unroll
    for (int it = 0; it < 16; ++it) {
        const int sl = it & 3;
        const int bb = it & 1;
        bf16x8 bnx[4];
        if (it < 14) {
            const unsigned short* bp = bw + (it + 2) * 2048;
#pragma unroll
            for (int f = 0; f < 4; ++f) bnx[f] = *(const bf16x8*)(bp + f * 512);
        }
        float av[8] = {Ar[sl][0].x, Ar[sl][0].y, Ar[sl][0].z, Ar[sl][0].w,
                       Ar[sl][1].x, Ar[sl][1].y, Ar[sl][1].z, Ar[sl][1].w};
        if (it < 12) {
            const float* ap = xr + (it + 4) * 32;
            Ar[sl][0] = *(const float4*)ap;
            Ar[sl][1] = *(const float4*)(ap + 4);
        }
        bf16x8 ah;
#pragma unroll
        for (int i = 0; i < 8; ++i) ah[i] = f2bf_hw(av[i]);
#pragma unroll
        for (int nb = 0; nb < 4; ++nb)
            acc[nb] = __builtin_amdgcn_mfma_f32_16x16x32_bf16(ah, Bf[bb][nb], acc[nb], 0, 0, 0);
        if (it < 14) {
#pragma unroll
            for (int f = 0; f < 4; ++f) Bf[bb][f] = bnx[f];
        }
    }

#pragma unroll
    for (int nb = 0; nb < 4; ++nb)
#pragma unroll
        for (int r = 0; r < 4; ++r)
            red[w][nb * 4 + r][l] = acc[nb][r];
    __syncthreads();

    float tot[4];
#pragma unroll
    for (int nb = 0; nb < 4; ++nb)
        tot[nb] = red[0][nb * 4 + w][l] + red[1][nb * 4 + w][l]
                + red[2][nb * 4 + w][l] + red[3][nb * 4 + w][l];

    float sig[4];
#pragma unroll
    for (int nb = 0; nb < 4; ++nb)
        sig[nb] = 1.0f / (1.0f + expf(-gates[nb * 16 + e0]));

    const int t = row0 + g * 4 + w;
    float lg[4];
    bool  act[4];
    int   lcnt = 0;
    float lmax = -3.4e38f;
#pragma unroll
    for (int nb = 0; nb < 4; ++nb) {
        lg[nb]  = tot[nb] - sig[nb];
        act[nb] = lg[nb] > 0.0f;
        if (act[nb]) { lcnt++; lmax = fmaxf(lmax, lg[nb]); }
    }
    int cnt = lcnt;
    float mx = lmax;
#pragma unroll
    for (int m = 1; m < 16; m <<= 1) {
        cnt += __shfl_xor(cnt, m, 16);
        mx   = fmaxf(mx, __shfl_xor(mx, m, 16));
    }

    float p[4], am[4];
    if (cnt > 0) {
        float ex[4], ls = 0.0f;
#pragma unroll
        for (int nb = 0; nb < 4; ++nb) {
            ex[nb] = act[nb] ? expf(lg[nb] - mx) : 0.0f;
            ls += ex[nb];
        }
        float Z = ls;
#pragma unroll
        for (int m = 1; m < 16; m <<= 1) Z += __shfl_xor(Z, m, 16);
        float rz = 1.0f / Z;
#pragma unroll
        for (int nb = 0; nb < 4; ++nb) {
            p[nb]  = ex[nb] * rz;
            am[nb] = act[nb] ? 1.0f : 0.0f;
        }
    } else {
        unsigned selm = 0;
        for (int it = 0; it < 32; ++it) {
            float bv = -3.4e38f;
            int   bi = 127;
#pragma unroll
            for (int nb = 0; nb < 4; ++nb) {
                if (!((selm >> nb) & 1)) {
                    float v = lg[nb];
                    int   e = nb * 16 + e0;
                    if (v > bv || (v == bv && e < bi)) { bv = v; bi = e; }
                }
            }
#pragma unroll
            for (int m = 1; m < 16; m <<= 1) {
                float ov = __shfl_xor(bv, m, 16);
                int   oi = __shfl_xor(bi, m, 16);
                if (ov > bv || (ov == bv && oi < bi)) { bv = ov; bi = oi; }
            }
            if ((bi & 15) == e0) selm |= 1u << (bi >> 4);
        }
#pragma unroll
        for (int nb = 0; nb < 4; ++nb) {
            bool s_ = (selm >> nb) & 1;
            p[nb]  = s_ ? (1.0f / 32.0f) : 0.0f;
            am[nb] = s_ ? 1.0f : 0.0f;
        }
        if (e0 == 0) atomicAdd(&out[FB_OFF], 1.0f);
    }

#pragma unroll
    for (int nb = 0; nb < 4; ++nb) {
        int idx = t * 64 + nb * 16 + e0;
        out[idx]          = p[nb];
        out[LG_OFF + idx] = lg[nb];
        out[AM_OFF + idx] = am[nb];
    }
}

// ---------------------------------------------------------------------------
extern "C" void kernel_launch(void* const* d_in, const int* in_sizes, int n_in,
                              void* d_out, int out_size, void* d_ws, size_t ws_size,
                              hipStream_t stream) {
    const float* x     = (const float*)d_in[0];   // [4,4096,2048] f32
    const float* sim   = (const float*)d_in[1];   // [2048,64] f32
    const float* gates = (const float*)d_in[2];   // [64] f32
    float* out = (float*)d_out;
    unsigned short* Bpk = (unsigned short*)d_ws;  // 256 KB prepacked B (bf16)

    gating_prepack<<<512, 256, 0, stream>>>(sim, Bpk, out);

    if (ws_size >= BPK_BYTES + PART_BYTES) {
        unsigned short* part = (unsigned short*)((char*)d_ws + BPK_BYTES);
        gating_gemm<<<512, 512, 0, stream>>>(x, Bpk, part);
        gating_epi<<<256, 256, 0, stream>>>(part, gates, out);
    } else {
        gating_mono<<<1024, 256, 0, stream>>>(x, Bpk, gates, out);
    }
}

// Round 10
// 36.434 us; speedup vs baseline: 1.1461x; 1.1461x over previous
//
#include <hip/hip_runtime.h>
#include <hip/hip_bf16.h>

// Problem constants (B=4, T=4096, C=2048, E=64)
#define N_TOK   16384
#define C_DIM   2048
#define E_DIM   64
#define P_OFF   (N_TOK * E_DIM)        // 1048576 — end of probs section
#define FB_OFF  P_OFF                  // fallback_count scalar
#define LG_OFF  (P_OFF + 1)            // logits section
#define AM_OFF  (2 * P_OFF + 1)        // activation_mask section

typedef __attribute__((ext_vector_type(8))) short bf16x8;  // 8 bf16 in 4 VGPRs
typedef __attribute__((ext_vector_type(4))) float f32x4;

static __device__ __forceinline__ unsigned short f2bf_rtn(float f) {
    unsigned u = __float_as_uint(f);
    unsigned r = u + 0x7FFFu + ((u >> 16) & 1u);   // round-to-nearest-even
    return (unsigned short)(r >> 16);
}
static __device__ __forceinline__ unsigned short f2bf_hw(float f) {
    __hip_bfloat16 h = __float2bfloat16(f);   // HW cvt; pairs fuse to v_cvt_pk_bf16_f32
    return *reinterpret_cast<unsigned short*>(&h);
}

// ---------------------------------------------------------------------------
// Kernel 1: prepack sim_matrix [2048,64] f32 -> bf16 (RTN) MFMA fragments.
// kk-step it (32 k): layout [it(64)][nb(4)][lane(64)][i(8)] shorts (256 KB).
// Content: lane l, elem i -> sim[it*32 + (l>>4)*8 + i][nb*16 + (l&15)]
// B-loads in the main kernel are lane-contiguous 16 B -> fully coalesced.
// Also zero-initializes the fallback counter in d_out.
// ---------------------------------------------------------------------------
__global__ void gating_prepack(const float* __restrict__ sim,
                               unsigned short* __restrict__ Bpk,
                               float* __restrict__ out) {
    int tid = blockIdx.x * 256 + threadIdx.x;
    if (tid == 0) out[FB_OFF] = 0.0f;
    if (tid >= C_DIM * E_DIM) return;
    int k = tid >> 6;
    int e = tid & 63;
    float v = sim[tid];                       // sim[k*64 + e]
    int it = k >> 5;                          // kk-step 0..63
    int gr = (k >> 3) & 3;
    int i  = k & 7;
    int lane = gr * 16 + (e & 15);
    int nb   = e >> 4;
    Bpk[it * 2048 + nb * 512 + lane * 8 + i] = f2bf_rtn(v);
}

// ---------------------------------------------------------------------------
// Kernel 2 (R10): coalesced-A GEMM + gating epilogue.
// Grid 1024 x 256 (4 waves, 4 blk/CU -> 16 waves/CU). Block = 16 tokens;
// wave w = K-quarter (16 kk-steps), processed as 8 chunks of 2 kk-steps.
//
// WHY: all R3-R9 schedules were neutral because A was loaded directly in
// MFMA-fragment layout -> each load instr = 16 rows x 8KB stride = 32
// discontiguous 64B segments. Per-CU MSHR limits then pin A-bandwidth at
// ~2 TB/s regardless of software pipelining. Here A is staged through a
// wave-private LDS tile with fully-coalesced global loads (4 rows x 256 B
// contiguous per instr, 100% utilization), f32->bf16 cvt during staging,
// and conflict-free swizzled ds_read_b128 fragment reads (1 per kk-step).
// No barriers in the loop (wave-private staging, lgkmcnt-ordered).
// T14 split: loads(ch+2) issued early, LDS writes(ch+1) late, reads(ch)
// first. B stays in a register dbuf from L2 (coalesced, load-after-use).
// ---------------------------------------------------------------------------
__global__ __launch_bounds__(256, 4)
void gating_main(const float* __restrict__ x,
                 const unsigned short* __restrict__ Bpk,
                 const float* __restrict__ gates,
                 float* __restrict__ out) {
    // 4 waves x 2 bufs x 2 KB staging (32 KB), reused as red[4][16][64] after barrier
    __shared__ __align__(16) char smem[32768];

    const int tid = threadIdx.x;
    const int l   = tid & 63;
    const int w   = tid >> 6;          // wave id == K-quarter == C/D reg r
    const int row0 = blockIdx.x * 16;
    const int g    = l >> 4;
    const int e0   = l & 15;

    // staging lane role: instr j covers rows j*4+srow, 16B-unit scol
    const int srow = l >> 4;           // 0..3
    const int scol = l & 15;           // 0..15 (16B units of the 256B row-chunk)

    const float* xq = x + (size_t)row0 * C_DIM + w * 512;
    char* Aw = smem + w * 4096;        // this wave's 2 staging bufs

    // B: per kk-step stride 2048 shorts; lane-contiguous fragment base
    const unsigned short* bw = Bpk + (size_t)w * 16 * 2048 + l * 8;

    f32x4 acc[4];
#pragma unroll
    for (int nb = 0; nb < 4; ++nb) acc[nb] = (f32x4)0.0f;

    // ---- staging helpers -------------------------------------------------
    // loads: chunk ch -> 4 coalesced float4 (rows j*4+srow, cols ch*64 + scol*4)
    float4 P[2][4];   // pending load data for 2 chunks
    auto loadA = [&](int ch, int p) {
#pragma unroll
        for (int j = 0; j < 4; ++j) {
            const int row = j * 4 + srow;
            P[p][j] = *(const float4*)(xq + (size_t)row * C_DIM + ch * 64 + scol * 4);
        }
    };
    // writes: cvt to bf16, swizzled ds_write_b64 into buf b
    auto writeA = [&](int p, int b) {
        char* dst = Aw + b * 2048;
#pragma unroll
        for (int j = 0; j < 4; ++j) {
            const int row = j * 4 + srow;
            ushort4 hv;
            hv.x = f2bf_hw(P[p][j].x); hv.y = f2bf_hw(P[p][j].y);
            hv.z = f2bf_hw(P[p][j].z); hv.w = f2bf_hw(P[p][j].w);
            const int wb = (row * 128 + scol * 8) ^ ((row & 7) << 4);
            *(ushort4*)(dst + wb) = hv;
        }
    };
    // fragment read: kk-step it (0/1) of buf b -> full 8-elem A fragment
    auto fragA = [&](int it, int b) -> bf16x8 {
        const int rb = (e0 * 128 + (it * 4 + g) * 16) ^ ((e0 & 7) << 4);
        return *(const bf16x8*)(Aw + b * 2048 + rb);
    };

    // ---- prologue --------------------------------------------------------
    loadA(0, 0);          // L(0)
    writeA(0, 0);         // W(0) -> buf0 (one exposed-latency hit, prologue only)
    loadA(1, 1);          // L(1) in flight
    bf16x8 Bf[2][4];
#pragma unroll
    for (int b2 = 0; b2 < 2; ++b2)
#pragma unroll
        for (int f = 0; f < 4; ++f)
            Bf[b2][f] = *(const bf16x8*)(bw + b2 * 2048 + f * 512);

    // ---- 8 chunks of 2 kk-steps ------------------------------------------
#pragma unroll
    for (int ch = 0; ch < 8; ++ch) {
        const int b = ch & 1;

        // (1) read current chunk's fragments (buf b written last iteration)
        bf16x8 af0 = fragA(0, b);
        bf16x8 af1 = fragA(1, b);

        // (2) issue loads for chunk ch+2 into pending slot (ch&1)
        if (ch < 6) loadA(ch + 2, ch & 1);

        // (3) compute: 2 kk-steps x 4 MFMA; B reloaded after use (dist 2)
#pragma unroll
        for (int it2 = 0; it2 < 2; ++it2) {
            const int itg = ch * 2 + it2;
            const bf16x8 af = it2 ? af1 : af0;
#pragma unroll
            for (int nb = 0; nb < 4; ++nb)
                acc[nb] = __builtin_amdgcn_mfma_f32_16x16x32_bf16(af, Bf[itg & 1][nb], acc[nb], 0, 0, 0);
            if (itg < 14) {
                const unsigned short* bp = bw + (itg + 2) * 2048;
#pragma unroll
                for (int f = 0; f < 4; ++f)
                    Bf[itg & 1][f] = *(const bf16x8*)(bp + f * 512);
            }
        }

        // (4) write chunk ch+1 into buf b^1 (its loads were issued last iter)
        if (ch < 7) writeA((ch + 1) & 1, b ^ 1);
    }

    // ---- cross-wave K reduction (reuse smem after barrier) ----------------
    __syncthreads();
    float (*red)[16][64] = (float(*)[16][64])smem;
#pragma unroll
    for (int nb = 0; nb < 4; ++nb)
#pragma unroll
        for (int r = 0; r < 4; ++r)
            red[w][nb * 4 + r][l] = acc[nb][r];
    __syncthreads();

    float tot[4];
#pragma unroll
    for (int nb = 0; nb < 4; ++nb)
        tot[nb] = red[0][nb * 4 + w][l] + red[1][nb * 4 + w][l]
                + red[2][nb * 4 + w][l] + red[3][nb * 4 + w][l];

    // ---- epilogue: wave w handles tokens t = row0 + g*4 + w ----
    float sig[4];
#pragma unroll
    for (int nb = 0; nb < 4; ++nb)
        sig[nb] = 1.0f / (1.0f + expf(-gates[nb * 16 + e0]));

    const int t = row0 + g * 4 + w;
    float lg[4];
    bool  act[4];
    int   lcnt = 0;
    float lmax = -3.4e38f;
#pragma unroll
    for (int nb = 0; nb < 4; ++nb) {
        lg[nb]  = tot[nb] - sig[nb];
        act[nb] = lg[nb] > 0.0f;
        if (act[nb]) { lcnt++; lmax = fmaxf(lmax, lg[nb]); }
    }
    int cnt = lcnt;
    float mx = lmax;
#pragma unroll
    for (int m = 1; m < 16; m <<= 1) {
        cnt += __shfl_xor(cnt, m, 16);
        mx   = fmaxf(mx, __shfl_xor(mx, m, 16));
    }

    float p[4], am[4];
    if (cnt > 0) {
        float ex[4], ls = 0.0f;
#pragma unroll
        for (int nb = 0; nb < 4; ++nb) {
            ex[nb] = act[nb] ? expf(lg[nb] - mx) : 0.0f;
            ls += ex[nb];
        }
        float Z = ls;
#pragma unroll
        for (int m = 1; m < 16; m <<= 1) Z += __shfl_xor(Z, m, 16);
        float rz = 1.0f / Z;
#pragma unroll
        for (int nb = 0; nb < 4; ++nb) {
            p[nb]  = ex[nb] * rz;
            am[nb] = act[nb] ? 1.0f : 0.0f;
        }
    } else {
        // fallback: top-32 of the 64 logits (ties -> lower expert index).
        // All logits <= 0 here, so probs are uniform 1/32 over the set.
        unsigned selm = 0;
        for (int it = 0; it < 32; ++it) {
            float bv = -3.4e38f;
            int   bi = 127;
#pragma unroll
            for (int nb = 0; nb < 4; ++nb) {
                if (!((selm >> nb) & 1)) {
                    float v = lg[nb];
                    int   e = nb * 16 + e0;
                    if (v > bv || (v == bv && e < bi)) { bv = v; bi = e; }
                }
            }
#pragma unroll
            for (int m = 1; m < 16; m <<= 1) {
                float ov = __shfl_xor(bv, m, 16);
                int   oi = __shfl_xor(bi, m, 16);
                if (ov > bv || (ov == bv && oi < bi)) { bv = ov; bi = oi; }
            }
            if ((bi & 15) == e0) selm |= 1u << (bi >> 4);
        }
#pragma unroll
        for (int nb = 0; nb < 4; ++nb) {
            bool s_ = (selm >> nb) & 1;
            p[nb]  = s_ ? (1.0f / 32.0f) : 0.0f;
            am[nb] = s_ ? 1.0f : 0.0f;
        }
        if (e0 == 0) atomicAdd(&out[FB_OFF], 1.0f);
    }

#pragma unroll
    for (int nb = 0; nb < 4; ++nb) {
        int idx = t * 64 + nb * 16 + e0;
        out[idx]          = p[nb];
        out[LG_OFF + idx] = lg[nb];
        out[AM_OFF + idx] = am[nb];
    }
}

// ---------------------------------------------------------------------------
extern "C" void kernel_launch(void* const* d_in, const int* in_sizes, int n_in,
                              void* d_out, int out_size, void* d_ws, size_t ws_size,
                              hipStream_t stream) {
    const float* x     = (const float*)d_in[0];   // [4,4096,2048] f32
    const float* sim   = (const float*)d_in[1];   // [2048,64] f32
    const float* gates = (const float*)d_in[2];   // [64] f32
    float* out = (float*)d_out;
    unsigned short* Bpk = (unsigned short*)d_ws;  // 256 KB prepacked B (bf16)

    gating_prepack<<<512, 256, 0, stream>>>(sim, Bpk, out);
    gating_main<<<1024, 256, 0, stream>>>(x, Bpk, gates, out);
}